// Round 7
// baseline (369.712 us; speedup 1.0000x reference)
//
#include <hip/hip_runtime.h>
#include <cmath>

#define NM 32768   // 512 * 64 matrices
#define ND 32      // matrix side
#define NSLICE 4   // global-atomic accumulator slices
#define SLICE_STRIDE 1088
#define FMBASE (NSLICE * SLICE_STRIDE)   // 4352: fm block base

typedef __attribute__((ext_vector_type(8))) short short8;     // 8 bf16 (4 VGPRs)
typedef __attribute__((ext_vector_type(16))) float f32x16;    // MFMA accumulator

// Broadcast from lane L within each 32-lane group (ds_swizzle BitMode: and=0, or=L, xor=0)
template<int L>
__device__ __forceinline__ float bcast32(float x) {
    return __int_as_float(__builtin_amdgcn_ds_swizzle(__float_as_int(x), (L << 5)));
}

// ---------- Cholesky, low-latency form. Lane r holds row r in a[0..31].
// Per column J: broadcasts of RAW a[J] (parallel, incl. pivot), then
// a[L] = fma(-a[J]*rcp(bJJ), bLJ, a[L]); normalize a[J] *= rsq(bJJ) off-path.
// Critical path per step: 1 bcast + rcp + fma  (vs 2 bcasts before).
template<int J, int L>
__device__ __forceinline__ void rank1_new(float (&a)[ND], float t) {
    if constexpr (L < ND) {
        float bLJ = bcast32<L>(a[J]);         // raw column-J value from lane L
        a[L] = fmaf(-t, bLJ, a[L]);
        rank1_new<J, L + 1>(a, t);
    }
}

template<int J>
__device__ __forceinline__ void chol_steps(float (&a)[ND], int r) {
    if constexpr (J < ND) {
        float bJJ = bcast32<J>(a[J]);         // raw pivot
        float inv = __builtin_amdgcn_rcpf(bJJ);
        float rs  = __builtin_amdgcn_rsqf(bJJ);
        float t = a[J] * inv;                 // lane J: t = 1
        rank1_new<J, J + 1>(a, t);            // Schur update with raw broadcasts
        a[J] *= rs;                           // final L[r][J] (lane J: sqrt(bJJ))
        chol_steps<J + 1>(a, r);
    }
}

union frag_u { short8 v; int i[4]; };

// Cross-half fragment exchange via __shfl_xor(.,32) (verified R4/R5).
__device__ __forceinline__ void build_frags(const frag_u& mine_lo, const frag_u& mine_hi,
                                            bool hi_half, frag_u& f0, frag_u& f1) {
    #pragma unroll
    for (int w = 0; w < 4; ++w) {
        int olo = __shfl_xor(mine_lo.i[w], 32);
        int ohi = __shfl_xor(mine_hi.i[w], 32);
        f0.i[w] = hi_half ? ohi : mine_lo.i[w];
        f1.i[w] = hi_half ? mine_hi.i[w] : olo;
    }
}

// Transform+pack one 16-wide k-slab into hi/lo fragments for both matrices.
template<int KB>
__device__ __forceinline__ void pack_quad(const float (&a)[ND], int r, float dval,
                                          float factor, const float* __restrict__ wsf,
                                          bool hi_half,
                                          frag_u& h0, frag_u& h1, frag_u& l0, frag_u& l1) {
    frag_u mlo_h, mhi_h, mlo_l, mhi_l;
    #pragma unroll
    for (int i = 0; i < 8; ++i) {
        int j0 = KB + i, j1 = KB + 8 + i;
        float t0 = fmaf(factor, a[j0], -wsf[j0 * ND + r]);
        float v0 = (j0 < r) ? t0 : ((j0 == r) ? dval : 0.0f);
        float t1 = fmaf(factor, a[j1], -wsf[j1 * ND + r]);
        float v1 = (j1 < r) ? t1 : ((j1 == r) ? dval : 0.0f);
        __bf16 hb0 = (__bf16)v0, hb1 = (__bf16)v1;
        mlo_h.v[i] = __builtin_bit_cast(short, hb0);
        mhi_h.v[i] = __builtin_bit_cast(short, hb1);
        mlo_l.v[i] = __builtin_bit_cast(short, (__bf16)(v0 - (float)hb0));
        mhi_l.v[i] = __builtin_bit_cast(short, (__bf16)(v1 - (float)hb1));
    }
    build_frags(mlo_h, mhi_h, hi_half, h0, h1);
    build_frags(mlo_l, mhi_l, hi_half, l0, l1);
}

// ws layout (floats):
//   slice s in [0,4): [s*1088 .. s*1088+1056] partial sums
//   [4352 .. 5375]: fmT = factor*sl_mean (transposed j*32+r); [5376..5407]: f*logd_mean; [5408]: factor
// L staged in d_out (k1 writes, k3 reads+overwrites), transposed: lm[j*32+r] = L[r][j].

__global__ __launch_bounds__(256, 6) void k1_stats(const float* __restrict__ X,
                                                   float* __restrict__ gacc,
                                                   float* __restrict__ Lbuf) {
    __shared__ float lacc[1057];
    int tid = threadIdx.x;
    for (int i = tid; i < 1057; i += 256) lacc[i] = 0.0f;
    __syncthreads();

    int lane = tid & 63;
    int r = lane & 31;
    int wave = tid >> 6;

    for (int pass = 0; pass < 2; ++pass) {
        int mp = (blockIdx.x * 2 + pass) * 4 + wave;   // matrix-pair id
        int mat = mp * 2 + (lane >> 5);
        const float* xm = X + (size_t)mat * (ND * ND);

        float a[ND];
        #pragma unroll
        for (int j = 0; j < ND; ++j) a[j] = xm[j * ND + r];  // row r via symmetry (coalesced)

        chol_steps<0>(a, r);

        // stage L for k3 (upper slots garbage, masked in k3)
        float* lm = Lbuf + (size_t)mat * (ND * ND);
        #pragma unroll
        for (int j = 0; j < ND; ++j) lm[j * ND + r] = a[j];

        float diag = a[0];
        #pragma unroll
        for (int j = 1; j < ND; ++j) diag = (r == j) ? a[j] : diag;
        float logd = logf(diag);

        float sq = logd * logd;
        #pragma unroll
        for (int j = 0; j < ND; ++j) if (j < r) sq = fmaf(a[j], a[j], sq);
        #pragma unroll
        for (int k = 1; k < 64; k <<= 1) sq += __shfl_xor(sq, k);
        if (lane == 0) atomicAdd(&lacc[1056], sq);

        #pragma unroll
        for (int j = 0; j < ND; ++j) if (j < r) atomicAdd(&lacc[j * ND + r], a[j]);
        atomicAdd(&lacc[1024 + r], logd);
    }

    __syncthreads();
    float* g = gacc + (size_t)(blockIdx.x & (NSLICE - 1)) * SLICE_STRIDE;
    for (int i = tid; i < 1057; i += 256) atomicAdd(&g[i], lacc[i]);
}

__global__ __launch_bounds__(256) void k2_final(const float* __restrict__ sscal,
                                                float* __restrict__ ws) {
    __shared__ float red[256];
    __shared__ float s2sh;
    __shared__ float sfactor;
    int tid = threadIdx.x;
    const float invM = 1.0f / (float)NM;

    float msq = 0.0f;
    for (int k = tid; k < 1057; k += 256) {
        float s = 0.0f;
        #pragma unroll
        for (int sl = 0; sl < NSLICE; ++sl) s += ws[sl * SLICE_STRIDE + k];
        if (k < 1056) {
            float m = s * invM;
            ws[FMBASE + k] = m;            // stash mean; scaled by factor below
            msq = fmaf(m, m, msq);
        } else {
            s2sh = s;
        }
    }
    red[tid] = msq;
    __syncthreads();
    for (int s = 128; s > 0; s >>= 1) {
        if (tid < s) red[tid] += red[tid + s];
        __syncthreads();
    }
    if (tid == 0) {
        float var = s2sh * invM - red[0];
        float f = sscal[0] / sqrtf(var);
        sfactor = f;
        ws[FMBASE + 1056] = f;
    }
    __syncthreads();
    float f = sfactor;
    for (int k = tid; k < 1056; k += 256) ws[FMBASE + k] *= f;
}

__global__ __launch_bounds__(256, 6) void k3_out(const float* __restrict__ wsf,
                                                 float* __restrict__ out) {
    int tid = threadIdx.x;
    int lane = tid & 63;
    int r = lane & 31;
    int wave = tid >> 6;
    int pair = blockIdx.x * 4 + wave;
    int mat = pair * 2 + (lane >> 5);
    bool hi_half = (lane >> 5) != 0;

    const float* lm = out + (size_t)mat * (ND * ND);
    float a[ND];
    #pragma unroll
    for (int j = 0; j < ND; ++j) a[j] = lm[j * ND + r];
    float diag = lm[r * ND + r];          // extra load, hits lines fetched above

    float factor = wsf[1056];
    float dval = expf(fmaf(factor, logf(diag), -wsf[1024 + r]));

    // Build ALL fragments first so a[] dies before the MFMA block (VGPR peak ~80)
    frag_u h0a, h1a, l0a, l1a, h0b, h1b, l0b, l1b;
    pack_quad<0>(a, r, dval, factor, wsf, hi_half, h0a, h1a, l0a, l1a);
    pack_quad<16>(a, r, dval, factor, wsf, hi_half, h0b, h1b, l0b, l1b);

    f32x16 acc0, acc1;
    #pragma unroll
    for (int g = 0; g < 16; ++g) { acc0[g] = 0.0f; acc1[g] = 0.0f; }

    acc0 = __builtin_amdgcn_mfma_f32_32x32x16_bf16(h0a.v, h0a.v, acc0, 0, 0, 0);
    acc1 = __builtin_amdgcn_mfma_f32_32x32x16_bf16(h1a.v, h1a.v, acc1, 0, 0, 0);
    acc0 = __builtin_amdgcn_mfma_f32_32x32x16_bf16(h0a.v, l0a.v, acc0, 0, 0, 0);
    acc1 = __builtin_amdgcn_mfma_f32_32x32x16_bf16(h1a.v, l1a.v, acc1, 0, 0, 0);
    acc0 = __builtin_amdgcn_mfma_f32_32x32x16_bf16(l0a.v, h0a.v, acc0, 0, 0, 0);
    acc1 = __builtin_amdgcn_mfma_f32_32x32x16_bf16(l1a.v, h1a.v, acc1, 0, 0, 0);
    acc0 = __builtin_amdgcn_mfma_f32_32x32x16_bf16(h0b.v, h0b.v, acc0, 0, 0, 0);
    acc1 = __builtin_amdgcn_mfma_f32_32x32x16_bf16(h1b.v, h1b.v, acc1, 0, 0, 0);
    acc0 = __builtin_amdgcn_mfma_f32_32x32x16_bf16(h0b.v, l0b.v, acc0, 0, 0, 0);
    acc1 = __builtin_amdgcn_mfma_f32_32x32x16_bf16(h1b.v, l1b.v, acc1, 0, 0, 0);
    acc0 = __builtin_amdgcn_mfma_f32_32x32x16_bf16(l0b.v, h0b.v, acc0, 0, 0, 0);
    acc1 = __builtin_amdgcn_mfma_f32_32x32x16_bf16(l1b.v, h1b.v, acc1, 0, 0, 0);

    // C/D layout (verified): col = lane&31, row = (g&3)+8*(g>>2)+4*(lane>>5)
    float* om0 = out + (size_t)(pair * 2) * (ND * ND);
    float* om1 = om0 + ND * ND;
    int col = lane & 31;
    int rb = (lane >> 5) * 4;
    #pragma unroll
    for (int g = 0; g < 16; ++g) {
        int row = (g & 3) + 8 * (g >> 2) + rb;
        om0[row * ND + col] = acc0[g];
        om1[row * ND + col] = acc1[g];
    }
}

extern "C" void kernel_launch(void* const* d_in, const int* in_sizes, int n_in,
                              void* d_out, int out_size, void* d_ws, size_t ws_size,
                              hipStream_t stream) {
    const float* X = (const float*)d_in[0];
    const float* s = (const float*)d_in[1];
    float* out = (float*)d_out;
    float* ws = (float*)d_ws;

    hipMemsetAsync(ws, 0, NSLICE * SLICE_STRIDE * sizeof(float), stream);
    hipLaunchKernelGGL(k1_stats, dim3(2048), dim3(256), 0, stream, X, ws, out);
    hipLaunchKernelGGL(k2_final, dim3(1), dim3(256), 0, stream, s, ws);
    hipLaunchKernelGGL(k3_out, dim3(4096), dim3(256), 0, stream, ws + FMBASE, out);
}